// Round 13
// baseline (67.741 us; speedup 1.0000x reference)
//
#include <hip/hip_runtime.h>

#define NQ 4096
#define MK 4096
#define DKC 512
#define DVC 512
#define SCALE 0.044151079f  // 1/sqrt(513)

typedef __attribute__((ext_vector_type(8))) short short8;
typedef __attribute__((ext_vector_type(4))) float f32x4;

__device__ __forceinline__ unsigned short f2bf(float x) {
  unsigned u = __float_as_uint(x);
  u += 0x7fffu + ((u >> 16) & 1u);
  return (unsigned short)(u >> 16);
}
__device__ __forceinline__ float bf2f(unsigned short h) {
  return __uint_as_float((unsigned)h << 16);
}

#define GLL16(g, l)                                                        \
  __builtin_amdgcn_global_load_lds(                                        \
      (const __attribute__((address_space(1))) unsigned int*)(g),          \
      (__attribute__((address_space(3))) unsigned int*)(l), 16, 0, 0)

// ---------------- fused prep: Qb=bf16(q*SCALE)+qatt | Kb | Vt ----------------
__global__ __launch_bounds__(256) void prep_all(const float* __restrict__ query,
                                                const float* __restrict__ q_k,
                                                const float* __restrict__ key,
                                                const float* __restrict__ value,
                                                unsigned short* __restrict__ Qb,
                                                unsigned short* __restrict__ Kb,
                                                unsigned short* __restrict__ Vt,
                                                float* __restrict__ qatt) {
  int b = blockIdx.x;
  if (b < 1024) {
    int n = b * 4 + (threadIdx.x >> 6);
    int lane = threadIdx.x & 63;
    const float4* qr = (const float4*)(query + (size_t)n * DKC + lane * 8);
    const float4* kr = (const float4*)(q_k + (size_t)n * DKC + lane * 8);
    float4 a0 = qr[0], a1 = qr[1];
    float4 b0 = kr[0], b1 = kr[1];
    float dot = a0.x * b0.x + a0.y * b0.y + a0.z * b0.z + a0.w * b0.w +
                a1.x * b1.x + a1.y * b1.y + a1.z * b1.z + a1.w * b1.w;
    unsigned short h[8] = {f2bf(a0.x * SCALE), f2bf(a0.y * SCALE), f2bf(a0.z * SCALE),
                           f2bf(a0.w * SCALE), f2bf(a1.x * SCALE), f2bf(a1.y * SCALE),
                           f2bf(a1.z * SCALE), f2bf(a1.w * SCALE)};
    *(short8*)(Qb + (size_t)n * DKC + lane * 8) = *(short8*)h;
#pragma unroll
    for (int off = 1; off < 64; off <<= 1) dot += __shfl_xor(dot, off, 64);
    if (lane == 0) qatt[n] = dot;
  } else if (b < 2048) {
    int i = (b - 1024) * 256 + threadIdx.x;
    const float4* src = (const float4*)key + (size_t)i * 2;
    float4 a0 = src[0], a1 = src[1];
    unsigned short h[8] = {f2bf(a0.x), f2bf(a0.y), f2bf(a0.z), f2bf(a0.w),
                           f2bf(a1.x), f2bf(a1.y), f2bf(a1.z), f2bf(a1.w)};
    *(short8*)(Kb + (size_t)i * 8) = *(short8*)h;
  } else {
    __shared__ float t[32][33];
    int bi = b - 2048;
    int tx = threadIdx.x & 31, ty = threadIdx.x >> 5;
    int m0 = (bi & 127) * 32;
    int d0 = (bi >> 7) * 32;
#pragma unroll
    for (int i = 0; i < 4; ++i)
      t[ty + i * 8][tx] = value[(size_t)(m0 + ty + i * 8) * DVC + d0 + tx];
    __syncthreads();
#pragma unroll
    for (int i = 0; i < 4; ++i)
      Vt[(size_t)(d0 + ty + i * 8) * MK + m0 + tx] = f2bf(t[tx][ty + i * 8]);
  }
}

// ---------------- gemm_s: 8-phase 256x256 tile, BK=64, 8 waves ----------------
// P''[4096][4096] bf16 = exp(Qb * Kb^T), rowsum_part[16][4096] f32.
// Double-buffered LDS 2x64KB; one 16KB half-tile staged per phase; vmcnt(2) at
// phases 3/7 only (counted, never 0 mid-loop); setprio around MFMA clusters.
#define PHASE_PRE()                                         \
  asm volatile("" ::: "memory");                            \
  __builtin_amdgcn_s_barrier();                             \
  asm volatile("s_waitcnt lgkmcnt(0)" ::: "memory");        \
  __builtin_amdgcn_sched_barrier(0);                        \
  __builtin_amdgcn_s_setprio(1)
#define PHASE_POST()                                        \
  __builtin_amdgcn_s_setprio(0);                            \
  asm volatile("" ::: "memory");                            \
  __builtin_amdgcn_s_barrier();                             \
  asm volatile("" ::: "memory")

__global__ __launch_bounds__(512, 2) void gemm_s(const unsigned short* __restrict__ Qb,
                                                 const unsigned short* __restrict__ Kb,
                                                 unsigned short* __restrict__ S,
                                                 float* __restrict__ rowsum_part) {
  __shared__ __align__(16) char lds[135168];  // 2x64KB staging; epi: sl 128K + rs 4K
  const int tid = threadIdx.x;
  const int wid = tid >> 6, lane = tid & 63, lr = lane & 15, lh = lane >> 4;
  const int wm = wid >> 2, wn = wid & 3;  // 2 x 4 waves, each 128m x 64n

  int bid = blockIdx.x;  // 256 WGs, bijective XCD swizzle
  int swz = (bid & 7) * 32 + (bid >> 3);
  const int tm = swz >> 4, tn = swz & 15;
  const size_t m0 = (size_t)tm * 256, n0 = (size_t)tn * 256;

  const char* abase = (const char*)Qb + m0 * 1024;  // row stride 1024 B
  const char* bbase = (const char*)Kb + n0 * 1024;

  // stage one half-tile: rows [h*128,+128) x 64 k of K-tile kt -> dbuf db
  auto stg = [&](const char* xbase, int kt, int h, int db, int boff) {
    char* dst = lds + db * 65536 + boff + h * 16384;
    const char* src = xbase + (size_t)(h * 128) * 1024 + kt * 128;
#pragma unroll
    for (int s = 0; s < 2; ++s) {
      int obase = wid * 2048 + s * 1024;
      int o = obase + lane * 16;
      int row = o >> 7;
      int g = ((o >> 4) & 7) ^ (row & 7);
      GLL16(src + (size_t)row * 1024 + g * 16, dst + obase);
    }
  };
  auto ard = [&](int fi, int ks, int db) -> short8 {
    return *(const short8*)(lds + db * 65536 + wm * 16384 + (fi * 16 + lr) * 128 +
                            ((((ks << 2) + lh) ^ (lr & 7)) << 4));
  };
  auto brd = [&](int fj, int ks, int db) -> short8 {
    return *(const short8*)(lds + db * 65536 + 32768 + (wn >> 1) * 16384 +
                            ((wn & 1) * 64 + fj * 16 + lr) * 128 +
                            ((((ks << 2) + lh) ^ (lr & 7)) << 4));
  };

  f32x4 acc[8][4];
#pragma unroll
  for (int i = 0; i < 8; ++i)
#pragma unroll
    for (int j = 0; j < 4; ++j) acc[i][j] = (f32x4){0.f, 0.f, 0.f, 0.f};
  short8 a[8][2], b[4][2];

  // prologue: kt0 fully + A-half0 of kt1 in flight
  stg(abase, 0, 0, 0, 0);
  stg(abase, 0, 1, 0, 0);
  stg(bbase, 0, 0, 0, 32768);
  stg(bbase, 0, 1, 0, 32768);
  stg(abase, 1, 0, 1, 0);
  asm volatile("s_waitcnt vmcnt(2)" ::: "memory");  // kt0's 4 halves landed
  __builtin_amdgcn_s_barrier();
  asm volatile("" ::: "memory");

  for (int it = 0; it < 4; ++it) {
    const int kt1 = 2 * it + 1;
    const bool more = (it < 3);
    // ===== P0: q(0,0) on kt0/db0; stage A-half1 kt1 -> db1 =====
#pragma unroll
    for (int fi = 0; fi < 4; ++fi)
#pragma unroll
      for (int ks = 0; ks < 2; ++ks) a[fi][ks] = ard(fi, ks, 0);
#pragma unroll
    for (int fj = 0; fj < 2; ++fj)
#pragma unroll
      for (int ks = 0; ks < 2; ++ks) b[fj][ks] = brd(fj, ks, 0);
    stg(abase, kt1, 1, 1, 0);
    PHASE_PRE();
#pragma unroll
    for (int fi = 0; fi < 4; ++fi)
#pragma unroll
      for (int fj = 0; fj < 2; ++fj)
#pragma unroll
        for (int ks = 0; ks < 2; ++ks)
          acc[fi][fj] = __builtin_amdgcn_mfma_f32_16x16x32_bf16(a[fi][ks], b[fj][ks], acc[fi][fj], 0, 0, 0);
    PHASE_POST();
    // ===== P1: q(0,1); stage B-half0 kt1 =====
#pragma unroll
    for (int fj = 2; fj < 4; ++fj)
#pragma unroll
      for (int ks = 0; ks < 2; ++ks) b[fj][ks] = brd(fj, ks, 0);
    stg(bbase, kt1, 0, 1, 32768);
    PHASE_PRE();
#pragma unroll
    for (int fi = 0; fi < 4; ++fi)
#pragma unroll
      for (int fj = 2; fj < 4; ++fj)
#pragma unroll
        for (int ks = 0; ks < 2; ++ks)
          acc[fi][fj] = __builtin_amdgcn_mfma_f32_16x16x32_bf16(a[fi][ks], b[fj][ks], acc[fi][fj], 0, 0, 0);
    PHASE_POST();
    // ===== P2: q(1,1); stage B-half1 kt1 =====
#pragma unroll
    for (int fi = 4; fi < 8; ++fi)
#pragma unroll
      for (int ks = 0; ks < 2; ++ks) a[fi][ks] = ard(fi, ks, 0);
    stg(bbase, kt1, 1, 1, 32768);
    PHASE_PRE();
#pragma unroll
    for (int fi = 4; fi < 8; ++fi)
#pragma unroll
      for (int fj = 2; fj < 4; ++fj)
#pragma unroll
        for (int ks = 0; ks < 2; ++ks)
          acc[fi][fj] = __builtin_amdgcn_mfma_f32_16x16x32_bf16(a[fi][ks], b[fj][ks], acc[fi][fj], 0, 0, 0);
    PHASE_POST();
    // ===== P3: q(1,0); stage A-half0 kt0+2 -> db0; vmcnt =====
    if (more) stg(abase, 2 * it + 2, 0, 0, 0);
    PHASE_PRE();
#pragma unroll
    for (int fi = 4; fi < 8; ++fi)
#pragma unroll
      for (int fj = 0; fj < 2; ++fj)
#pragma unroll
        for (int ks = 0; ks < 2; ++ks)
          acc[fi][fj] = __builtin_amdgcn_mfma_f32_16x16x32_bf16(a[fi][ks], b[fj][ks], acc[fi][fj], 0, 0, 0);
    __builtin_amdgcn_s_setprio(0);
    if (more) asm volatile("s_waitcnt vmcnt(2)" ::: "memory");  // kt1 halves landed
    else      asm volatile("s_waitcnt vmcnt(0)" ::: "memory");
    asm volatile("" ::: "memory");
    __builtin_amdgcn_s_barrier();
    asm volatile("" ::: "memory");
    // ===== P4: q(0,0) on kt1/db1; stage A-half1 kt0+2 =====
#pragma unroll
    for (int fi = 0; fi < 4; ++fi)
#pragma unroll
      for (int ks = 0; ks < 2; ++ks) a[fi][ks] = ard(fi, ks, 1);
#pragma unroll
    for (int fj = 0; fj < 2; ++fj)
#pragma unroll
      for (int ks = 0; ks < 2; ++ks) b[fj][ks] = brd(fj, ks, 1);
    if (more) stg(abase, 2 * it + 2, 1, 0, 0);
    PHASE_PRE();
#pragma unroll
    for (int fi = 0; fi < 4; ++fi)
#pragma unroll
      for (int fj = 0; fj < 2; ++fj)
#pragma unroll
        for (int ks = 0; ks < 2; ++ks)
          acc[fi][fj] = __builtin_amdgcn_mfma_f32_16x16x32_bf16(a[fi][ks], b[fj][ks], acc[fi][fj], 0, 0, 0);
    PHASE_POST();
    // ===== P5: q(0,1); stage B-half0 kt0+2 =====
#pragma unroll
    for (int fj = 2; fj < 4; ++fj)
#pragma unroll
      for (int ks = 0; ks < 2; ++ks) b[fj][ks] = brd(fj, ks, 1);
    if (more) stg(bbase, 2 * it + 2, 0, 0, 32768);
    PHASE_PRE();
#pragma unroll
    for (int fi = 0; fi < 4; ++fi)
#pragma unroll
      for (int fj = 2; fj < 4; ++fj)
#pragma unroll
        for (int ks = 0; ks < 2; ++ks)
          acc[fi][fj] = __builtin_amdgcn_mfma_f32_16x16x32_bf16(a[fi][ks], b[fj][ks], acc[fi][fj], 0, 0, 0);
    PHASE_POST();
    // ===== P6: q(1,1); stage B-half1 kt0+2 =====
#pragma unroll
    for (int fi = 4; fi < 8; ++fi)
#pragma unroll
      for (int ks = 0; ks < 2; ++ks) a[fi][ks] = ard(fi, ks, 1);
    if (more) stg(bbase, 2 * it + 2, 1, 0, 32768);
    PHASE_PRE();
#pragma unroll
    for (int fi = 4; fi < 8; ++fi)
#pragma unroll
      for (int fj = 2; fj < 4; ++fj)
#pragma unroll
        for (int ks = 0; ks < 2; ++ks)
          acc[fi][fj] = __builtin_amdgcn_mfma_f32_16x16x32_bf16(a[fi][ks], b[fj][ks], acc[fi][fj], 0, 0, 0);
    PHASE_POST();
    // ===== P7: q(1,0); stage A-half0 kt1+2 -> db1; vmcnt =====
    if (more) stg(abase, 2 * it + 3, 0, 1, 0);
    PHASE_PRE();
#pragma unroll
    for (int fi = 4; fi < 8; ++fi)
#pragma unroll
      for (int fj = 0; fj < 2; ++fj)
#pragma unroll
        for (int ks = 0; ks < 2; ++ks)
          acc[fi][fj] = __builtin_amdgcn_mfma_f32_16x16x32_bf16(a[fi][ks], b[fj][ks], acc[fi][fj], 0, 0, 0);
    __builtin_amdgcn_s_setprio(0);
    if (more) asm volatile("s_waitcnt vmcnt(2)" ::: "memory");  // kt0+2 halves landed
    asm volatile("" ::: "memory");
    __builtin_amdgcn_s_barrier();
    asm volatile("" ::: "memory");
  }

  // epilogue: e = exp(acc); rowsums (16 strips); bf16 bounce [256][256]; stores
  unsigned short* sl = (unsigned short*)lds;          // 128 KB
  float* rs = (float*)(lds + 131072);                 // [4][256] f32
  float rsum[8][4];
#pragma unroll
  for (int fi = 0; fi < 8; ++fi)
#pragma unroll
    for (int r = 0; r < 4; ++r) rsum[fi][r] = 0.f;
#pragma unroll
  for (int fi = 0; fi < 8; ++fi)
#pragma unroll
    for (int fj = 0; fj < 4; ++fj)
#pragma unroll
      for (int r = 0; r < 4; ++r) {
        int m = wm * 128 + fi * 16 + lh * 4 + r;
        int n = wn * 64 + fj * 16 + lr;
        float e = __expf(acc[fi][fj][r]);
        sl[m * 256 + n] = f2bf(e);
        rsum[fi][r] += e;
      }
#pragma unroll
  for (int fi = 0; fi < 8; ++fi)
#pragma unroll
    for (int r = 0; r < 4; ++r) {
      float v = rsum[fi][r];
      v += __shfl_xor(v, 1, 64);
      v += __shfl_xor(v, 2, 64);
      v += __shfl_xor(v, 4, 64);
      v += __shfl_xor(v, 8, 64);
      if (lr == 0) rs[wn * 256 + wm * 128 + fi * 16 + lh * 4 + r] = v;
    }
  __syncthreads();
  if (tid < 256) {
    float s = rs[tid] + rs[256 + tid] + rs[512 + tid] + rs[768 + tid];
    rowsum_part[(size_t)tn * NQ + m0 + tid] = s;
  }
#pragma unroll
  for (int i = 0; i < 16; ++i) {
    int o = i * 8192 + tid * 16;
    int row = o >> 9, colb = o & 511;  // 512 B per bf16 tile row (256 elems)
    *(uint4*)((char*)S + (m0 + row) * 8192 + n0 * 2 + colb) = *(const uint4*)((const char*)sl + o);
  }
}

// ---------------- gemm_o_part: part[ksl][4096][512] bf16 = P''(K-slice) * V ----------------
__global__ __launch_bounds__(256, 2) void gemm_o_part(const unsigned short* __restrict__ P,
                                                      const unsigned short* __restrict__ Vt,
                                                      unsigned short* __restrict__ part) {
  __shared__ __align__(16) char lds[65536];  // A@0 (32K), B@32K (32K)
  const int tid = threadIdx.x;
  const int wid = tid >> 6, lane = tid & 63, lr = lane & 15, lh = lane >> 4;
  const int wm = wid >> 1, wn = wid & 1;

  int bid = blockIdx.x;                   // 512 WGs, bijective XCD swizzle
  int swz = (bid & 7) * 64 + (bid >> 3);
  const int mt = swz >> 4;
  const int nt = (swz >> 2) & 3;
  const int ksl = swz & 3;
  const size_t m0 = (size_t)mt * 128, n0 = (size_t)nt * 128;

  f32x4 acc[4][4];
#pragma unroll
  for (int i = 0; i < 4; ++i)
#pragma unroll
    for (int j = 0; j < 4; ++j) acc[i][j] = (f32x4){0.f, 0.f, 0.f, 0.f};

  const char* abase = (const char*)P + m0 * 8192 + (size_t)ksl * 2048;
  const char* bbase = (const char*)Vt + n0 * 8192 + (size_t)ksl * 2048;

  for (int ks = 0; ks < 8; ++ks) {
    const int kb = ks * 256;
    {
      char* al = lds;
      char* bl = lds + 32768;
#pragma unroll
      for (int s = 0; s < 8; ++s) {
        int obase = wid * 8192 + s * 1024;
        int o = obase + lane * 16;
        int row = o >> 8;
        int colg = ((o >> 4) & 15) ^ (row & 7);
        GLL16(abase + (size_t)row * 8192 + kb + colg * 16, al + obase);
        GLL16(bbase + (size_t)row * 8192 + kb + colg * 16, bl + obase);
      }
    }
    __syncthreads();
#pragma unroll
    for (int kk = 0; kk < 4; ++kk) {
      short8 af[4], bf[4];
#pragma unroll
      for (int i = 0; i < 4; ++i) {
        int ar = wm * 64 + i * 16 + lr;
        af[i] = *(const short8*)(lds + ar * 256 + ((((kk << 2) + lh) ^ (ar & 7)) << 4));
        int br = wn * 64 + i * 16 + lr;
        bf[i] = *(const short8*)(lds + 32768 + br * 256 + ((((kk << 2) + lh) ^ (br & 7)) << 4));
      }
#pragma unroll
      for (int i = 0; i < 4; ++i)
#pragma unroll
        for (int j = 0; j < 4; ++j)
          acc[i][j] = __builtin_amdgcn_mfma_f32_16x16x32_bf16(af[i], bf[j], acc[i][j], 0, 0, 0);
    }
    __syncthreads();
  }

  unsigned short* sl = (unsigned short*)lds;
#pragma unroll
  for (int i = 0; i < 4; ++i)
#pragma unroll
    for (int j = 0; j < 4; ++j)
#pragma unroll
      for (int r = 0; r < 4; ++r) {
        int m = wm * 64 + i * 16 + lh * 4 + r;
        int n = wn * 64 + j * 16 + lr;
        sl[m * 128 + n] = f2bf(acc[i][j][r]);
      }
  __syncthreads();
  char* pbase = (char*)part + (size_t)ksl * NQ * DVC * 2;
#pragma unroll
  for (int i = 0; i < 8; ++i) {
    int o = i * 4096 + tid * 16;
    int row = o >> 8, colb = o & 255;
    *(uint4*)(pbase + (m0 + row) * 1024 + n0 * 2 + colb) = *(const uint4*)((const char*)sl + o);
  }
}

// ---------------- combine2: inv folded (16 strips); out = q_v*qa + sum(part)*inv ------
__global__ __launch_bounds__(256) void combine2(const unsigned short* __restrict__ part,
                                                const float* __restrict__ rowsum_part,
                                                const float* __restrict__ qatt,
                                                const float* __restrict__ q_v,
                                                float* __restrict__ out) {
  __shared__ float inv_s[4];
  const int b = blockIdx.x;  // 4 rows per block
  const int t = threadIdx.x;
  if (t < 64) {
    int r = t >> 4, p = t & 15;
    float v = rowsum_part[(size_t)p * NQ + b * 4 + r];
    v += __shfl_xor(v, 1, 64);
    v += __shfl_xor(v, 2, 64);
    v += __shfl_xor(v, 4, 64);
    v += __shfl_xor(v, 8, 64);
    if (p == 0) inv_s[r] = 1.0f / (v + __expf(qatt[b * 4 + r] * SCALE));
  }
  __syncthreads();
  int r = t >> 6;
  int d8 = (t & 63) * 8;
  int n = b * 4 + r;
  float qa = qatt[n];
  float iv = inv_s[r];
  size_t off = (size_t)n * DVC + d8;
  float rr[8] = {0.f, 0.f, 0.f, 0.f, 0.f, 0.f, 0.f, 0.f};
#pragma unroll
  for (int w = 0; w < 4; ++w) {
    short8 po = *(const short8*)(part + (size_t)w * NQ * DVC + off);
#pragma unroll
    for (int j = 0; j < 8; ++j) rr[j] += bf2f((unsigned short)po[j]);
  }
  const float4* qv = (const float4*)(q_v + off);
  float4 qv0 = qv[0], qv1 = qv[1];
  float4 o0 = {qv0.x * qa + rr[0] * iv, qv0.y * qa + rr[1] * iv, qv0.z * qa + rr[2] * iv,
               qv0.w * qa + rr[3] * iv};
  float4 o1 = {qv1.x * qa + rr[4] * iv, qv1.y * qa + rr[5] * iv, qv1.z * qa + rr[6] * iv,
               qv1.w * qa + rr[7] * iv};
  float4* op = (float4*)(out + off);
  op[0] = o0;
  op[1] = o1;
}

extern "C" void kernel_launch(void* const* d_in, const int* in_sizes, int n_in,
                              void* d_out, int out_size, void* d_ws, size_t ws_size,
                              hipStream_t stream) {
  const float* query = (const float*)d_in[0];
  const float* q_k = (const float*)d_in[1];
  const float* q_v = (const float*)d_in[2];
  const float* key = (const float*)d_in[3];
  const float* value = (const float*)d_in[4];
  float* out = (float*)d_out;

  char* ws = (char*)d_ws;
  unsigned short* Qb = (unsigned short*)(ws);                 // 4 MB
  unsigned short* Kb = (unsigned short*)(ws + (4u << 20));    // 4 MB
  unsigned short* Vt = (unsigned short*)(ws + (8u << 20));    // 4 MB
  unsigned short* S = (unsigned short*)(ws + (12u << 20));    // 32 MB (holds P'' = exp)
  float* qatt = (float*)(ws + (44u << 20));                   // 16 KB
  unsigned short* part = (unsigned short*)(ws + (45u << 20)); // 16 MB (4 x 4 MB bf16)
  float* rowsum_part = (float*)(ws + (61u << 20));            // 256 KB (16 x 4096 f32)

  prep_all<<<dim3(4096), dim3(256), 0, stream>>>(query, q_k, key, value, Qb, Kb, Vt, qatt);
  gemm_s<<<dim3(256), dim3(512), 0, stream>>>(Qb, Kb, S, rowsum_part);
  gemm_o_part<<<dim3(512), dim3(256), 0, stream>>>(S, Vt, part);
  combine2<<<dim3(1024), dim3(256), 0, stream>>>(part, rowsum_part, qatt, q_v, out);
}

// Round 14
// 65.768 us; speedup vs baseline: 1.0300x; 1.0300x over previous
//
#include <hip/hip_runtime.h>

#define NQ 4096
#define MK 4096
#define DKC 512
#define DVC 512
#define SCALE 0.044151079f  // 1/sqrt(513)

typedef __attribute__((ext_vector_type(8))) short short8;
typedef __attribute__((ext_vector_type(4))) float f32x4;

__device__ __forceinline__ unsigned short f2bf(float x) {
  unsigned u = __float_as_uint(x);
  u += 0x7fffu + ((u >> 16) & 1u);
  return (unsigned short)(u >> 16);
}
__device__ __forceinline__ float bf2f(unsigned short h) {
  return __uint_as_float((unsigned)h << 16);
}

#define GLL16(g, l)                                                        \
  __builtin_amdgcn_global_load_lds(                                        \
      (const __attribute__((address_space(1))) unsigned int*)(g),          \
      (__attribute__((address_space(3))) unsigned int*)(l), 16, 0, 0)

// ---------------- fused prep: Qb=bf16(q*SCALE)+qatt | Kb | Vt ----------------
__global__ __launch_bounds__(256) void prep_all(const float* __restrict__ query,
                                                const float* __restrict__ q_k,
                                                const float* __restrict__ key,
                                                const float* __restrict__ value,
                                                unsigned short* __restrict__ Qb,
                                                unsigned short* __restrict__ Kb,
                                                unsigned short* __restrict__ Vt,
                                                float* __restrict__ qatt) {
  int b = blockIdx.x;
  if (b < 1024) {
    int n = b * 4 + (threadIdx.x >> 6);
    int lane = threadIdx.x & 63;
    const float4* qr = (const float4*)(query + (size_t)n * DKC + lane * 8);
    const float4* kr = (const float4*)(q_k + (size_t)n * DKC + lane * 8);
    float4 a0 = qr[0], a1 = qr[1];
    float4 b0 = kr[0], b1 = kr[1];
    float dot = a0.x * b0.x + a0.y * b0.y + a0.z * b0.z + a0.w * b0.w +
                a1.x * b1.x + a1.y * b1.y + a1.z * b1.z + a1.w * b1.w;
    unsigned short h[8] = {f2bf(a0.x * SCALE), f2bf(a0.y * SCALE), f2bf(a0.z * SCALE),
                           f2bf(a0.w * SCALE), f2bf(a1.x * SCALE), f2bf(a1.y * SCALE),
                           f2bf(a1.z * SCALE), f2bf(a1.w * SCALE)};
    *(short8*)(Qb + (size_t)n * DKC + lane * 8) = *(short8*)h;
#pragma unroll
    for (int off = 1; off < 64; off <<= 1) dot += __shfl_xor(dot, off, 64);
    if (lane == 0) qatt[n] = dot;
  } else if (b < 2048) {
    int i = (b - 1024) * 256 + threadIdx.x;
    const float4* src = (const float4*)key + (size_t)i * 2;
    float4 a0 = src[0], a1 = src[1];
    unsigned short h[8] = {f2bf(a0.x), f2bf(a0.y), f2bf(a0.z), f2bf(a0.w),
                           f2bf(a1.x), f2bf(a1.y), f2bf(a1.z), f2bf(a1.w)};
    *(short8*)(Kb + (size_t)i * 8) = *(short8*)h;
  } else {
    __shared__ float t[32][33];
    int bi = b - 2048;
    int tx = threadIdx.x & 31, ty = threadIdx.x >> 5;
    int m0 = (bi & 127) * 32;
    int d0 = (bi >> 7) * 32;
#pragma unroll
    for (int i = 0; i < 4; ++i)
      t[ty + i * 8][tx] = value[(size_t)(m0 + ty + i * 8) * DVC + d0 + tx];
    __syncthreads();
#pragma unroll
    for (int i = 0; i < 4; ++i)
      Vt[(size_t)(d0 + ty + i * 8) * MK + m0 + tx] = f2bf(t[tx][ty + i * 8]);
  }
}

// ---------------- gemm_s: P''[4096][4096] bf16 = exp(Qb * Kb^T) + row-partial sums ----
// R12-proven 2-barrier structure: 128x128 tile, BK=64, 4 blocks/CU.
__global__ __launch_bounds__(256, 4) void gemm_s(const unsigned short* __restrict__ Qb,
                                                 const unsigned short* __restrict__ Kb,
                                                 unsigned short* __restrict__ S,
                                                 float* __restrict__ rowsum_part) {
  __shared__ __align__(16) char lds[33792];  // staging 32K; epilogue: sl 32K + rs 1K
  const int tid = threadIdx.x;
  const int wid = tid >> 6, lane = tid & 63, lr = lane & 15, lh = lane >> 4;
  const int wm = wid >> 1, wn = wid & 1;

  int bid = blockIdx.x;                    // 1024 WGs, bijective XCD swizzle
  int swz = (bid & 7) * 128 + (bid >> 3);
  const int tm = swz >> 5, tn = swz & 31;
  const size_t m0 = (size_t)tm * 128, n0 = (size_t)tn * 128;

  f32x4 acc[4][4];
#pragma unroll
  for (int i = 0; i < 4; ++i)
#pragma unroll
    for (int j = 0; j < 4; ++j) acc[i][j] = (f32x4){0.f, 0.f, 0.f, 0.f};

  const char* abase = (const char*)Qb + m0 * 1024;  // row stride 1024 B
  const char* bbase = (const char*)Kb + n0 * 1024;

  for (int ks = 0; ks < 8; ++ks) {
    const int kb = ks * 128;
    {
      char* al = lds;
      char* bl = lds + 16384;
#pragma unroll
      for (int s = 0; s < 4; ++s) {
        int obase = wid * 4096 + s * 1024;
        int o = obase + lane * 16;
        int row = o >> 7;
        int colg = ((o >> 4) & 7) ^ (row & 7);
        GLL16(abase + (size_t)row * 1024 + kb + colg * 16, al + obase);
        GLL16(bbase + (size_t)row * 1024 + kb + colg * 16, bl + obase);
      }
    }
    __syncthreads();
#pragma unroll
    for (int kk = 0; kk < 2; ++kk) {
      short8 af[4], bf[4];
#pragma unroll
      for (int i = 0; i < 4; ++i) {
        int ar = wm * 64 + i * 16 + lr;
        af[i] = *(const short8*)(lds + ar * 128 + ((((kk << 2) + lh) ^ (lr & 7)) << 4));
        int br = wn * 64 + i * 16 + lr;
        bf[i] = *(const short8*)(lds + 16384 + br * 128 + ((((kk << 2) + lh) ^ (lr & 7)) << 4));
      }
#pragma unroll
      for (int i = 0; i < 4; ++i)
#pragma unroll
        for (int j = 0; j < 4; ++j)
          acc[i][j] = __builtin_amdgcn_mfma_f32_16x16x32_bf16(af[i], bf[j], acc[i][j], 0, 0, 0);
    }
    __syncthreads();
  }

  // epilogue: e = exp(acc); pack to LDS; accumulate per-row sums in registers
  unsigned short* sl = (unsigned short*)lds;
  float* rs = (float*)(lds + 32768);  // [2][128] cross-wave rowsum partials
  float rsum[4][4];
#pragma unroll
  for (int i = 0; i < 4; ++i)
#pragma unroll
    for (int r = 0; r < 4; ++r) rsum[i][r] = 0.f;
#pragma unroll
  for (int i = 0; i < 4; ++i)
#pragma unroll
    for (int j = 0; j < 4; ++j)
#pragma unroll
      for (int r = 0; r < 4; ++r) {
        int m = wm * 64 + i * 16 + lh * 4 + r;
        int n = wn * 64 + j * 16 + lr;
        float e = __expf(acc[i][j][r]);
        sl[m * 128 + n] = f2bf(e);
        rsum[i][r] += e;
      }
#pragma unroll
  for (int i = 0; i < 4; ++i)
#pragma unroll
    for (int r = 0; r < 4; ++r) {
      float v = rsum[i][r];
      v += __shfl_xor(v, 1, 64);
      v += __shfl_xor(v, 2, 64);
      v += __shfl_xor(v, 4, 64);
      v += __shfl_xor(v, 8, 64);
      if (lr == 0) rs[wn * 128 + wm * 64 + i * 16 + lh * 4 + r] = v;
    }
  __syncthreads();
  if (tid < 128) rowsum_part[(size_t)tn * NQ + m0 + tid] = rs[tid] + rs[128 + tid];
#pragma unroll
  for (int i = 0; i < 8; ++i) {
    int o = i * 4096 + tid * 16;
    int row = o >> 8, colb = o & 255;
    *(uint4*)((char*)S + (m0 + row) * 8192 + n0 * 2 + colb) = *(const uint4*)((const char*)sl + o);
  }
}

// ---------------- gemm_o_part: part[ksl][4096][512] bf16 = P''(K-slice) * V ----------------
// 128x128 tile, 256 thr (2x2 waves, 64x64, 4x4 acc), BK=64, DOUBLE-BUFFERED 2x32KB,
// counted vmcnt(8): next step's 8 loads stay in flight under this step's MFMAs.
// Split-K=4 -> 512 WGs, 2 blocks/CU.
__global__ __launch_bounds__(256, 2) void gemm_o_part(const unsigned short* __restrict__ P,
                                                      const unsigned short* __restrict__ Vt,
                                                      unsigned short* __restrict__ part) {
  __shared__ __align__(16) char lds[65536];  // [A0 16K][B0 16K][A1 16K][B1 16K]
  const int tid = threadIdx.x;
  const int wid = tid >> 6, lane = tid & 63, lr = lane & 15, lh = lane >> 4;
  const int wm = wid >> 1, wn = wid & 1;

  int bid = blockIdx.x;                   // 512 WGs, bijective XCD swizzle (512%8==0)
  int swz = (bid & 7) * 64 + (bid >> 3);
  const int mt = swz >> 4;                // 32 m-tiles of 128
  const int nt = (swz >> 2) & 3;          // 4 n-tiles of 128
  const int ksl = swz & 3;                // 4 K-slices of 1024
  const size_t m0 = (size_t)mt * 128, n0 = (size_t)nt * 128;

  f32x4 acc[4][4];
#pragma unroll
  for (int i = 0; i < 4; ++i)
#pragma unroll
    for (int j = 0; j < 4; ++j) acc[i][j] = (f32x4){0.f, 0.f, 0.f, 0.f};

  const char* abase = (const char*)P + m0 * 8192 + (size_t)ksl * 2048;   // P row 8192 B
  const char* bbase = (const char*)Vt + n0 * 8192 + (size_t)ksl * 2048;  // Vt row 8192 B

  // stage K-step ks into buffer b: A 128x64 bf16 (16KB, 128B rows) + B 128x64 (16KB)
  auto stage = [&](int ks, int b) {
    const int kb = ks * 128;  // 64 elems = 128 B within the slice
    char* al = lds + b * 32768;
    char* bl = al + 16384;
#pragma unroll
    for (int s = 0; s < 4; ++s) {
      int obase = wid * 4096 + s * 1024;  // 4 waves x 4KB, 1KB per GLL16
      int o = obase + lane * 16;
      int row = o >> 7;                   // 128 B per LDS row
      int colg = ((o >> 4) & 7) ^ (row & 7);
      GLL16(abase + (size_t)row * 8192 + kb + colg * 16, al + obase);
      GLL16(bbase + (size_t)row * 8192 + kb + colg * 16, bl + obase);
    }
  };

  stage(0, 0);  // prologue: 8 outstanding

  for (int ks = 0; ks < 16; ++ks) {
    const int cur = ks & 1;
    if (ks + 1 < 16) {
      stage(ks + 1, cur ^ 1);                           // 8 more in flight (16 total)
      asm volatile("s_waitcnt vmcnt(8)" ::: "memory");  // current step's 8 landed
    } else {
      asm volatile("s_waitcnt vmcnt(0)" ::: "memory");
    }
    __builtin_amdgcn_s_barrier();
    asm volatile("" ::: "memory");

    const char* al = lds + cur * 32768;
    const char* bl = al + 16384;
#pragma unroll
    for (int kk = 0; kk < 2; ++kk) {
      short8 af[4], bf[4];
#pragma unroll
      for (int i = 0; i < 4; ++i) {
        int ar = wm * 64 + i * 16 + lr;
        af[i] = *(const short8*)(al + ar * 128 + ((((kk << 2) + lh) ^ (lr & 7)) << 4));
        int br = wn * 64 + i * 16 + lr;
        bf[i] = *(const short8*)(bl + br * 128 + ((((kk << 2) + lh) ^ (lr & 7)) << 4));
      }
#pragma unroll
      for (int i = 0; i < 4; ++i)
#pragma unroll
        for (int j = 0; j < 4; ++j)
          acc[i][j] = __builtin_amdgcn_mfma_f32_16x16x32_bf16(af[i], bf[j], acc[i][j], 0, 0, 0);
    }

    asm volatile("" ::: "memory");
    __builtin_amdgcn_s_barrier();  // all waves done reading buf[cur] before overwrite
    asm volatile("" ::: "memory");
  }

  // epilogue: bf16 bounce [128][128] + coalesced 16B stores to part[ksl]
  unsigned short* sl = (unsigned short*)lds;
#pragma unroll
  for (int i = 0; i < 4; ++i)
#pragma unroll
    for (int j = 0; j < 4; ++j)
#pragma unroll
      for (int r = 0; r < 4; ++r) {
        int m = wm * 64 + i * 16 + lh * 4 + r;
        int n = wn * 64 + j * 16 + lr;
        sl[m * 128 + n] = f2bf(acc[i][j][r]);
      }
  __syncthreads();
  char* pbase = (char*)part + (size_t)ksl * NQ * DVC * 2;
#pragma unroll
  for (int i = 0; i < 8; ++i) {
    int o = i * 4096 + tid * 16;
    int row = o >> 8, colb = o & 255;  // 256 B per bf16 tile row (128 elems)
    *(uint4*)(pbase + (m0 + row) * 1024 + n0 * 2 + colb) = *(const uint4*)((const char*)sl + o);
  }
}

// ---------------- combine2: inv folded (32 strips); out = q_v*qa + sum(part)*inv ------
__global__ __launch_bounds__(256) void combine2(const unsigned short* __restrict__ part,
                                                const float* __restrict__ rowsum_part,
                                                const float* __restrict__ qatt,
                                                const float* __restrict__ q_v,
                                                float* __restrict__ out) {
  __shared__ float inv_s[4];
  const int b = blockIdx.x;  // 4 rows per block
  const int t = threadIdx.x;
  if (t < 128) {
    int r = t >> 5, p = t & 31;
    float v = rowsum_part[(size_t)p * NQ + b * 4 + r];
#pragma unroll
    for (int off = 1; off < 32; off <<= 1) v += __shfl_xor(v, off, 32);
    if (p == 0) inv_s[r] = 1.0f / (v + __expf(qatt[b * 4 + r] * SCALE));
  }
  __syncthreads();
  int r = t >> 6;
  int d8 = (t & 63) * 8;
  int n = b * 4 + r;
  float qa = qatt[n];
  float iv = inv_s[r];
  size_t off = (size_t)n * DVC + d8;
  float rr[8] = {0.f, 0.f, 0.f, 0.f, 0.f, 0.f, 0.f, 0.f};
#pragma unroll
  for (int w = 0; w < 4; ++w) {
    short8 po = *(const short8*)(part + (size_t)w * NQ * DVC + off);
#pragma unroll
    for (int j = 0; j < 8; ++j) rr[j] += bf2f((unsigned short)po[j]);
  }
  const float4* qv = (const float4*)(q_v + off);
  float4 qv0 = qv[0], qv1 = qv[1];
  float4 o0 = {qv0.x * qa + rr[0] * iv, qv0.y * qa + rr[1] * iv, qv0.z * qa + rr[2] * iv,
               qv0.w * qa + rr[3] * iv};
  float4 o1 = {qv1.x * qa + rr[4] * iv, qv1.y * qa + rr[5] * iv, qv1.z * qa + rr[6] * iv,
               qv1.w * qa + rr[7] * iv};
  float4* op = (float4*)(out + off);
  op[0] = o0;
  op[1] = o1;
}

extern "C" void kernel_launch(void* const* d_in, const int* in_sizes, int n_in,
                              void* d_out, int out_size, void* d_ws, size_t ws_size,
                              hipStream_t stream) {
  const float* query = (const float*)d_in[0];
  const float* q_k = (const float*)d_in[1];
  const float* q_v = (const float*)d_in[2];
  const float* key = (const float*)d_in[3];
  const float* value = (const float*)d_in[4];
  float* out = (float*)d_out;

  char* ws = (char*)d_ws;
  unsigned short* Qb = (unsigned short*)(ws);                 // 4 MB
  unsigned short* Kb = (unsigned short*)(ws + (4u << 20));    // 4 MB
  unsigned short* Vt = (unsigned short*)(ws + (8u << 20));    // 4 MB
  unsigned short* S = (unsigned short*)(ws + (12u << 20));    // 32 MB (holds P'' = exp)
  float* qatt = (float*)(ws + (44u << 20));                   // 16 KB
  unsigned short* part = (unsigned short*)(ws + (45u << 20)); // 16 MB (4 x 4 MB bf16)
  float* rowsum_part = (float*)(ws + (61u << 20));            // 512 KB (32 x 4096 f32)

  prep_all<<<dim3(4096), dim3(256), 0, stream>>>(query, q_k, key, value, Qb, Kb, Vt, qatt);
  gemm_s<<<dim3(1024), dim3(256), 0, stream>>>(Qb, Kb, S, rowsum_part);
  gemm_o_part<<<dim3(512), dim3(256), 0, stream>>>(S, Vt, part);
  combine2<<<dim3(1024), dim3(256), 0, stream>>>(part, rowsum_part, qatt, q_v, out);
}